// Round 8
// baseline (542.379 us; speedup 1.0000x reference)
//
#include <hip/hip_runtime.h>
#include <hip/hip_bf16.h>
#include <stdint.h>

#define NTOK 8192
#define DDIM 1024
#define HDIM 4096
#define NEXP 8
#define MAXWL1 48   // BM=256 work-list
#define MAXWL2 72   // BM=128 work-list

typedef __attribute__((ext_vector_type(4))) float f32x4;
typedef __attribute__((ext_vector_type(8))) short s16x8;
typedef __attribute__((ext_vector_type(8))) unsigned short u16x8;

__device__ __forceinline__ unsigned short f2bf(float f) {
  union { float f; unsigned int u; } v; v.f = f;
  unsigned int u = v.u;
  u += 0x7FFFu + ((u >> 16) & 1u);   // round-to-nearest-even
  return (unsigned short)(u >> 16);
}

typedef __attribute__((address_space(3))) unsigned char lds_u8;
typedef const __attribute__((address_space(1))) unsigned char glb_u8;

__device__ __forceinline__ void load_lds16(const void* g, void* l) {
  __builtin_amdgcn_global_load_lds((glb_u8*)g, (lds_u8*)l, 16, 0, 0);
}

// ---------------- gate + top-1 routing ----------------
__global__ __launch_bounds__(256) void gate_kernel(
    const float* __restrict__ x, const float* __restrict__ Wg,
    const float* __restrict__ bg, int* __restrict__ counts,
    int* __restrict__ lists) {
  const int lane = threadIdx.x & 63;
  const int tok = blockIdx.x * 4 + (threadIdx.x >> 6);
  const float* xr = x + (size_t)tok * DDIM;
  double acc[NEXP];
#pragma unroll
  for (int e = 0; e < NEXP; ++e) acc[e] = 0.0;
#pragma unroll 4
  for (int it = 0; it < DDIM / 64; ++it) {
    const int d = it * 64 + lane;
    const float xv = xr[d];
    const f32x4 w0 = *(const f32x4*)(Wg + (size_t)d * NEXP);
    const f32x4 w1 = *(const f32x4*)(Wg + (size_t)d * NEXP + 4);
#pragma unroll
    for (int j = 0; j < 4; ++j) {
      acc[j]     += (double)xv * (double)w0[j];
      acc[4 + j] += (double)xv * (double)w1[j];
    }
  }
#pragma unroll
  for (int e = 0; e < NEXP; ++e) {
    double v = acc[e];
#pragma unroll
    for (int off = 32; off > 0; off >>= 1) v += __shfl_xor(v, off, 64);
    acc[e] = v;
  }
  if (lane == 0) {
    int best = 0;
    double bv = acc[0] + (double)bg[0];
#pragma unroll
    for (int e = 1; e < NEXP; ++e) {
      const double v = acc[e] + (double)bg[e];
      if (v > bv) { bv = v; best = e; }   // strict > : first max wins (np argmax)
    }
    const int pos = atomicAdd(&counts[best], 1);
    lists[best * NTOK + pos] = tok;
  }
}

// ---- prefix sum + two work-lists: wl1 (BM=256), wl2 (BM=128) ----
__global__ void offs_kernel(const int* __restrict__ counts, int* __restrict__ offs,
                            int* __restrict__ wl1, int* __restrict__ wl2) {
  int s = 0;
#pragma unroll
  for (int e = 0; e < NEXP; ++e) { offs[e] = s; s += counts[e]; }
  offs[NEXP] = s;
  int n1 = 0, n2 = 0;
  for (int e = 0; e < NEXP; ++e) {
    const int nb1 = (counts[e] + 255) >> 8;
    for (int b = 0; b < nb1; ++b) wl1[n1++] = (e << 20) | b;
    const int nb2 = (counts[e] + 127) >> 7;
    for (int b = 0; b < nb2; ++b) wl2[n2++] = (e << 20) | b;
  }
  offs[NEXP + 1] = n1;
  offs[NEXP + 2] = n2;
}

// -------- gather tokens into expert-sorted order, convert to bf16 --------
__global__ __launch_bounds__(256) void gather_conv_kernel(
    const float* __restrict__ x, const int* __restrict__ offs,
    const int* __restrict__ lists, int* __restrict__ stok,
    unsigned short* __restrict__ xbs) {
  const int p = blockIdx.x * 4 + (threadIdx.x >> 6);   // sorted position
  const int lane = threadIdx.x & 63;
  int e = 0;
#pragma unroll
  for (int k = 1; k < NEXP; ++k) e += (p >= offs[k]) ? 1 : 0;
  const int tok = lists[e * NTOK + (p - offs[e])];
  if (lane == 0) stok[p] = tok;
  const float* src = x + (size_t)tok * DDIM + lane * 16;
  unsigned short* dst = xbs + (size_t)p * DDIM + lane * 16;
#pragma unroll
  for (int q = 0; q < 2; ++q) {
    const f32x4 a = *(const f32x4*)(src + q * 8);
    const f32x4 b = *(const f32x4*)(src + q * 8 + 4);
    u16x8 o;
#pragma unroll
    for (int j = 0; j < 4; ++j) { o[j] = f2bf(a[j]); o[4 + j] = f2bf(b[j]); }
    *(u16x8*)(dst + q * 8) = o;
  }
}

// -- transpose + convert: in [E][R][C] fp32 -> out [E][C][R] bf16; 16B writes --
__global__ __launch_bounds__(256) void transpose_conv_kernel(
    const float* __restrict__ in, unsigned short* __restrict__ out,
    int R, int C) {
  __shared__ unsigned short T[64][66];
  const int e = blockIdx.z;
  const float* ine = in + (size_t)e * R * C;
  unsigned short* oute = out + (size_t)e * C * R;
  const int c0 = blockIdx.x * 64, r0 = blockIdx.y * 64;
  const int t = threadIdx.x;
  const int tr = t >> 4, tc4 = (t & 15) * 4;
#pragma unroll
  for (int p = 0; p < 4; ++p) {
    const int r = tr + p * 16;
    const f32x4 v = *(const f32x4*)(ine + (size_t)(r0 + r) * C + c0 + tc4);
#pragma unroll
    for (int j = 0; j < 4; ++j) T[r][tc4 + j] = f2bf(v[j]);
  }
  __syncthreads();
  const int cc = t >> 3, rr8 = (t & 7) * 8;
#pragma unroll
  for (int p = 0; p < 2; ++p) {
    const int c = cc + p * 32;
    u16x8 o;
#pragma unroll
    for (int j = 0; j < 8; ++j) o[j] = T[rr8 + j][c];
    *(u16x8*)(oute + (size_t)(c0 + c) * R + r0 + rr8) = o;
  }
}

// ---- grouped GEMM: BK=32, ring-2 LDS, 8 waves, 2-3 blocks/CU, natural layout ----
// A: bf16 [NTOK][K] expert-sorted rows. Bt: bf16 [E][N][K] (K-contiguous rows).
// BK=32 rows are 64B -> natural layout is bank-conflict-free for ds_read_b128
// (bank group = 16*(row&1)+slot*4: 8 groups x 8 lanes = minimum schedule).
// NO swizzle anywhere (round-6's swizzle CAUSED the 7M conflicts).
// Phase: vmcnt(0) [prev-issued tile landed, short wait] -> barrier ->
//        stage(next tile, flies under compute) -> 12 ds_read -> setprio+MFMA.
// 2-3 co-resident blocks/CU hide the drain (m114 implicit overlap).
template <int BM, int BN, int WN, int K, int N, int MAXWLT, bool FUSE1>
__global__ __launch_bounds__(512, 2) void ffn_kernel(
    const unsigned short* __restrict__ A, const unsigned short* __restrict__ Bt,
    const float* __restrict__ bias, const int* __restrict__ counts,
    const int* __restrict__ offs, const int* __restrict__ wl,
    const int* __restrict__ stok, unsigned short* __restrict__ outb,
    float* __restrict__ outf, int nwl_idx) {
  constexpr int WM = 8 / WN;
  constexpr int MF = BM / (WM * 16);
  constexpr int NF = BN / (WN * 16);
  constexpr int ISS_A = BM / 128;    // 512 thr x 16B = 8KB = 128 rows of 64B
  constexpr int ISS_B = BN / 128;
  constexpr int NT = K / 32;
  constexpr int NCB = N / BN;
  constexpr int NWG = NCB * MAXWLT;
  static_assert((NWG & 7) == 0 && (NT & 1) == 0 && NT >= 4, "");

  const int d = blockIdx.x;
  const int logical = (d & 7) * (NWG / 8) + (d >> 3);  // XCD chunking
  const int col0 = (logical / MAXWLT) * BN;            // chunk shares B-panel
  const int wli = logical % MAXWLT;
  if (wli >= offs[nwl_idx]) return;
  const int wle = wl[wli];
  const int e = wle >> 20;
  const int bx = wle & 0xFFFFF;
  const int cnt = counts[e];
  const int row0 = offs[e] + bx * BM;

  __shared__ __align__(16) unsigned short As0[BM * 32], Bs0[BN * 32];
  __shared__ __align__(16) unsigned short As1[BM * 32], Bs1[BN * 32];

  const int tid = threadIdx.x;
  const int lane = tid & 63;
  const int w = tid >> 6;
  const int wm = w / WN;
  const int wn = w % WN;
  const int fr = lane & 15;
  const int fj = lane >> 4;

  // staging: thread -> LDS row i*128+(tid>>2), 16B-slot tid&3; source linear.
  const int kslot = (tid & 3) * 8;   // ushort offset within row
  const int rb = tid >> 2;
  const unsigned short* srcA[ISS_A];
#pragma unroll
  for (int i = 0; i < ISS_A; ++i) {
    int gr = row0 + i * 128 + rb;
    if (gr > NTOK - 1) gr = NTOK - 1;   // clamp: garbage rows masked in epilogue
    srcA[i] = A + (size_t)gr * K + kslot;
  }
  const unsigned short* Bte = Bt + (size_t)e * N * K;
  const unsigned short* srcB[ISS_B];
#pragma unroll
  for (int i = 0; i < ISS_B; ++i)
    srcB[i] = Bte + (size_t)(col0 + i * 128 + rb) * K + kslot;

  f32x4 acc[MF][NF];
#pragma unroll
  for (int m = 0; m < MF; ++m)
#pragma unroll
    for (int n = 0; n < NF; ++n) acc[m][n] = f32x4{0.f, 0.f, 0.f, 0.f};

  auto stage = [&](unsigned short* dA, unsigned short* dB, int kel) {
#pragma unroll
    for (int i = 0; i < ISS_A; ++i)
      load_lds16(srcA[i] + kel, dA + i * 128 * 32 + tid * 8);
#pragma unroll
    for (int i = 0; i < ISS_B; ++i)
      load_lds16(srcB[i] + kel, dB + i * 128 * 32 + tid * 8);
  };

  auto body = [&](const unsigned short* pA, const unsigned short* pB,
                  unsigned short* nA, unsigned short* nB, int knext,
                  bool do_stage) {
    asm volatile("s_waitcnt vmcnt(0)" ::: "memory");  // current tile landed
    __builtin_amdgcn_s_barrier();
    asm volatile("" ::: "memory");
    if (do_stage) stage(nA, nB, knext);   // next tile flies under this compute
    s16x8 af[MF], bf[NF];
#pragma unroll
    for (int m = 0; m < MF; ++m)
      af[m] = *(const s16x8*)(pA + (wm * MF * 16 + m * 16 + fr) * 32 + fj * 8);
#pragma unroll
    for (int n = 0; n < NF; ++n)
      bf[n] = *(const s16x8*)(pB + (wn * NF * 16 + n * 16 + fr) * 32 + fj * 8);
    __builtin_amdgcn_s_setprio(1);
#pragma unroll
    for (int m = 0; m < MF; ++m)
#pragma unroll
      for (int n = 0; n < NF; ++n)
        acc[m][n] = __builtin_amdgcn_mfma_f32_16x16x32_bf16(af[m], bf[n],
                                                            acc[m][n], 0, 0, 0);
    __builtin_amdgcn_s_setprio(0);
  };

  stage(As0, Bs0, 0);   // prologue
#pragma unroll 1
  for (int t = 0; t < NT - 2; t += 2) {
    body(As0, Bs0, As1, Bs1, (t + 1) * 32, true);
    body(As1, Bs1, As0, Bs0, (t + 2) * 32, true);
  }
  body(As0, Bs0, As1, Bs1, (NT - 1) * 32, true);
  body(As1, Bs1, nullptr, nullptr, 0, false);

  // epilogue
#pragma unroll
  for (int n = 0; n < NF; ++n) {
    const int col = col0 + wn * NF * 16 + n * 16 + fr;
    const float bv = bias[e * N + col];
#pragma unroll
    for (int m = 0; m < MF; ++m) {
#pragma unroll
      for (int j = 0; j < 4; ++j) {
        const int rl = wm * MF * 16 + m * 16 + fj * 4 + j;
        if (bx * BM + rl < cnt) {
          if constexpr (FUSE1) {
            outb[(size_t)(row0 + rl) * N + col] = f2bf(fmaxf(acc[m][n][j] + bv, 0.f));
          } else {
            outf[(size_t)stok[row0 + rl] * N + col] = acc[m][n][j] + bv;
          }
        }
      }
    }
  }
}

extern "C" void kernel_launch(void* const* d_in, const int* in_sizes, int n_in,
                              void* d_out, int out_size, void* d_ws, size_t ws_size,
                              hipStream_t stream) {
  (void)in_sizes; (void)n_in; (void)out_size;
  const float* x  = (const float*)d_in[0];
  const float* Wg = (const float*)d_in[1];
  const float* bg = (const float*)d_in[2];
  const float* W1 = (const float*)d_in[3];
  const float* b1 = (const float*)d_in[4];
  const float* W2 = (const float*)d_in[5];
  const float* b2 = (const float*)d_in[6];
  float* out = (float*)d_out;

  char* ws = (char*)d_ws;
  const size_t OFF_CNT = 0;                                    // 8 ints
  const size_t OFF_OFF = 128;                                  // offs[0..10]
  const size_t OFF_WL1 = 256;                                  // MAXWL1 ints
  const size_t OFF_WL2 = 256 + MAXWL1 * 4;                     // MAXWL2 ints
  const size_t OFF_LST = 1024;                                 // E*NTOK ints (256 KB)
  const size_t OFF_STK = OFF_LST + (size_t)NEXP * NTOK * 4;    // NTOK ints
  const size_t OFF_XBS = OFF_STK + (size_t)NTOK * 4;           // NTOK*D bf16 (16 MB)
  const size_t OFF_HS  = OFF_XBS + (size_t)NTOK * DDIM * 2;    // NTOK*H bf16 (64 MB)
  const size_t OFF_WT  = OFF_HS + (size_t)NTOK * HDIM * 2;     // E*D*H bf16 (64 MB)
  const size_t NEED    = OFF_WT + (size_t)NEXP * DDIM * HDIM * 2;
  if (ws_size < NEED) return;

  int* counts = (int*)(ws + OFF_CNT);
  int* offs   = (int*)(ws + OFF_OFF);
  int* wl1    = (int*)(ws + OFF_WL1);
  int* wl2    = (int*)(ws + OFF_WL2);
  int* lists  = (int*)(ws + OFF_LST);
  int* stok   = (int*)(ws + OFF_STK);
  unsigned short* xbs = (unsigned short*)(ws + OFF_XBS);
  unsigned short* Hs  = (unsigned short*)(ws + OFF_HS);
  unsigned short* Wt  = (unsigned short*)(ws + OFF_WT);

  hipMemsetAsync(counts, 0, 128, stream);
  gate_kernel<<<NTOK / 4, 256, 0, stream>>>(x, Wg, bg, counts, lists);
  offs_kernel<<<1, 1, 0, stream>>>(counts, offs, wl1, wl2);
  gather_conv_kernel<<<NTOK / 4, 256, 0, stream>>>(x, offs, lists, stok, xbs);

  // W1 [E][D][H] -> Wt [E][H][D]
  transpose_conv_kernel<<<dim3(HDIM / 64, DDIM / 64, NEXP), 256, 0, stream>>>(
      W1, Wt, DDIM, HDIM);
  // ffn1: Hs[pos] = relu(xbs[pos] @ W1[e] + b1[e]) ; 256x256, BK=32, 2 blk/CU
  ffn_kernel<256, 256, 4, DDIM, HDIM, MAXWL1, true>
      <<<dim3((HDIM / 256) * MAXWL1), 512, 0, stream>>>(
          xbs, Wt, b1, counts, offs, wl1, stok, Hs, nullptr, NEXP + 1);
  // W2 [E][H][D] -> Wt [E][D][H]  (reuse buffer after ffn1)
  transpose_conv_kernel<<<dim3(DDIM / 64, HDIM / 64, NEXP), 256, 0, stream>>>(
      W2, Wt, HDIM, DDIM);
  // ffn2: out[stok[pos]] = Hs[pos] @ W2[e] + b2[e] ; 128x256, BK=32, 3 blk/CU
  ffn_kernel<128, 256, 4, HDIM, DDIM, MAXWL2, false>
      <<<dim3((DDIM / 256) * MAXWL2), 512, 0, stream>>>(
          Hs, Wt, b2, counts, offs, wl2, stok, nullptr, out, NEXP + 2);
}

// Round 9
// 509.566 us; speedup vs baseline: 1.0644x; 1.0644x over previous
//
#include <hip/hip_runtime.h>
#include <hip/hip_bf16.h>
#include <stdint.h>

#define NTOK 8192
#define DDIM 1024
#define HDIM 4096
#define NEXP 8
#define MAXWL 48   // BM=256 work-list

typedef __attribute__((ext_vector_type(4))) float f32x4;
typedef __attribute__((ext_vector_type(8))) short s16x8;
typedef __attribute__((ext_vector_type(8))) unsigned short u16x8;

__device__ __forceinline__ unsigned short f2bf(float f) {
  union { float f; unsigned int u; } v; v.f = f;
  unsigned int u = v.u;
  u += 0x7FFFu + ((u >> 16) & 1u);   // round-to-nearest-even
  return (unsigned short)(u >> 16);
}

typedef __attribute__((address_space(3))) unsigned char lds_u8;
typedef const __attribute__((address_space(1))) unsigned char glb_u8;

__device__ __forceinline__ void load_lds16(const void* g, void* l) {
  __builtin_amdgcn_global_load_lds((glb_u8*)g, (lds_u8*)l, 16, 0, 0);
}

template <int VM> __device__ __forceinline__ void wait_vm() {
  if constexpr (VM == 8)      asm volatile("s_waitcnt vmcnt(8)" ::: "memory");
  else if constexpr (VM == 6) asm volatile("s_waitcnt vmcnt(6)" ::: "memory");
  else if constexpr (VM == 4) asm volatile("s_waitcnt vmcnt(4)" ::: "memory");
  else if constexpr (VM == 3) asm volatile("s_waitcnt vmcnt(3)" ::: "memory");
  else                        asm volatile("s_waitcnt vmcnt(0)" ::: "memory");
}

// ---------------- gate + top-1 routing ----------------
__global__ __launch_bounds__(256) void gate_kernel(
    const float* __restrict__ x, const float* __restrict__ Wg,
    const float* __restrict__ bg, int* __restrict__ counts,
    int* __restrict__ lists) {
  const int lane = threadIdx.x & 63;
  const int tok = blockIdx.x * 4 + (threadIdx.x >> 6);
  const float* xr = x + (size_t)tok * DDIM;
  double acc[NEXP];
#pragma unroll
  for (int e = 0; e < NEXP; ++e) acc[e] = 0.0;
#pragma unroll 4
  for (int it = 0; it < DDIM / 64; ++it) {
    const int d = it * 64 + lane;
    const float xv = xr[d];
    const f32x4 w0 = *(const f32x4*)(Wg + (size_t)d * NEXP);
    const f32x4 w1 = *(const f32x4*)(Wg + (size_t)d * NEXP + 4);
#pragma unroll
    for (int j = 0; j < 4; ++j) {
      acc[j]     += (double)xv * (double)w0[j];
      acc[4 + j] += (double)xv * (double)w1[j];
    }
  }
#pragma unroll
  for (int e = 0; e < NEXP; ++e) {
    double v = acc[e];
#pragma unroll
    for (int off = 32; off > 0; off >>= 1) v += __shfl_xor(v, off, 64);
    acc[e] = v;
  }
  if (lane == 0) {
    int best = 0;
    double bv = acc[0] + (double)bg[0];
#pragma unroll
    for (int e = 1; e < NEXP; ++e) {
      const double v = acc[e] + (double)bg[e];
      if (v > bv) { bv = v; best = e; }   // strict > : first max wins (np argmax)
    }
    const int pos = atomicAdd(&counts[best], 1);
    lists[best * NTOK + pos] = tok;
  }
}

// ---- prefix sum + block work-list (BM=256): wl[i]=(e<<20)|bx, nwl in offs[9] ----
__global__ void offs_kernel(const int* __restrict__ counts, int* __restrict__ offs,
                            int* __restrict__ wl) {
  int s = 0;
#pragma unroll
  for (int e = 0; e < NEXP; ++e) { offs[e] = s; s += counts[e]; }
  offs[NEXP] = s;
  int n = 0;
  for (int e = 0; e < NEXP; ++e) {
    const int nb = (counts[e] + 255) >> 8;
    for (int b = 0; b < nb; ++b) wl[n++] = (e << 20) | b;
  }
  offs[NEXP + 1] = n;
}

// -------- gather tokens into expert-sorted order, convert to bf16 --------
__global__ __launch_bounds__(256) void gather_conv_kernel(
    const float* __restrict__ x, const int* __restrict__ offs,
    const int* __restrict__ lists, int* __restrict__ stok,
    unsigned short* __restrict__ xbs) {
  const int p = blockIdx.x * 4 + (threadIdx.x >> 6);   // sorted position
  const int lane = threadIdx.x & 63;
  int e = 0;
#pragma unroll
  for (int k = 1; k < NEXP; ++k) e += (p >= offs[k]) ? 1 : 0;
  const int tok = lists[e * NTOK + (p - offs[e])];
  if (lane == 0) stok[p] = tok;
  const float* src = x + (size_t)tok * DDIM + lane * 16;
  unsigned short* dst = xbs + (size_t)p * DDIM + lane * 16;
#pragma unroll
  for (int q = 0; q < 2; ++q) {
    const f32x4 a = *(const f32x4*)(src + q * 8);
    const f32x4 b = *(const f32x4*)(src + q * 8 + 4);
    u16x8 o;
#pragma unroll
    for (int j = 0; j < 4; ++j) { o[j] = f2bf(a[j]); o[4 + j] = f2bf(b[j]); }
    *(u16x8*)(dst + q * 8) = o;
  }
}

// -- transpose + convert: in [E][R][C] fp32 -> out [E][C][R] bf16; 16B writes --
__global__ __launch_bounds__(256) void transpose_conv_kernel(
    const float* __restrict__ in, unsigned short* __restrict__ out,
    int R, int C) {
  __shared__ unsigned short T[64][66];
  const int e = blockIdx.z;
  const float* ine = in + (size_t)e * R * C;
  unsigned short* oute = out + (size_t)e * C * R;
  const int c0 = blockIdx.x * 64, r0 = blockIdx.y * 64;
  const int t = threadIdx.x;
  const int tr = t >> 4, tc4 = (t & 15) * 4;
#pragma unroll
  for (int p = 0; p < 4; ++p) {
    const int r = tr + p * 16;
    const f32x4 v = *(const f32x4*)(ine + (size_t)(r0 + r) * C + c0 + tc4);
#pragma unroll
    for (int j = 0; j < 4; ++j) T[r][tc4 + j] = f2bf(v[j]);
  }
  __syncthreads();
  const int cc = t >> 3, rr8 = (t & 7) * 8;
#pragma unroll
  for (int p = 0; p < 2; ++p) {
    const int c = cc + p * 32;
    u16x8 o;
#pragma unroll
    for (int j = 0; j < 8; ++j) o[j] = T[rr8 + j][c];
    *(u16x8*)(oute + (size_t)(c0 + c) * R + r0 + rr8) = o;
  }
}

// ---- grouped GEMM: 256xBN, BK=32, ring-4 LDS, counted-vmcnt depth-3 (R6 + fixes) ----
// A: bf16 [NTOK][K] expert-sorted rows. Bt: bf16 [E][N][K] (K-contiguous rows).
// Conflict-free BK=32 swizzle (quarter-wave analysis): LDS slot s of row r holds
// global 16B-slot s ^ ((r>>1)&3); read slot = fj ^ ((fr>>1)&3)  -> each 16-lane
// group spreads 8 bank-groups x 2 lanes (free per m136).
// Pipeline: stage tile t+3 during phase t; wait vmcnt(2*S) (tiles t+1,t+2 in
// flight), S = VMEM instrs per stage. Never drain to 0 in main loop (T4).
template <int BN, int K, int N, bool FUSE1>
__global__ __launch_bounds__(512, 2) void ffn_kernel(
    const unsigned short* __restrict__ A, const unsigned short* __restrict__ Bt,
    const float* __restrict__ bias, const int* __restrict__ counts,
    const int* __restrict__ offs, const int* __restrict__ wl,
    const int* __restrict__ stok, unsigned short* __restrict__ outb,
    float* __restrict__ outf) {
  constexpr int BM = 256;
  constexpr int ISS_B = BN / 128;
  constexpr int S = 2 + ISS_B;        // VMEM instrs per stage
  constexpr int NF = BN / 64;         // 4 N-waves
  constexpr int NT = K / 32;
  constexpr int NCB = N / BN;
  constexpr int NWG = NCB * MAXWL;
  static_assert((NWG & 7) == 0 && (NT & 3) == 0 && NT >= 8, "");

  const int d = blockIdx.x;
  const int logical = (d & 7) * (NWG / 8) + (d >> 3);  // XCD chunking
  const int col0 = (logical / MAXWL) * BN;             // chunk shares B-panel
  const int wli = logical % MAXWL;
  if (wli >= offs[NEXP + 1]) return;
  const int wle = wl[wli];
  const int e = wle >> 20;
  const int bx = wle & 0xFFFFF;
  const int cnt = counts[e];
  const int row0 = offs[e] + bx * BM;

  __shared__ __align__(16) unsigned short As0[BM * 32], Bs0[BN * 32];
  __shared__ __align__(16) unsigned short As1[BM * 32], Bs1[BN * 32];
  __shared__ __align__(16) unsigned short As2[BM * 32], Bs2[BN * 32];
  __shared__ __align__(16) unsigned short As3[BM * 32], Bs3[BN * 32];

  const int tid = threadIdx.x;
  const int lane = tid & 63;
  const int w = tid >> 6;
  const int wm = w >> 2;          // 2 M-waves (128 rows each)
  const int wn = w & 3;           // 4 N-waves
  const int fr = lane & 15;
  const int fj = lane >> 4;

  // staging: thread -> LDS row rb=i*128+(tid>>2), slot tid&3 (16B units);
  // source slot pre-swizzled: (tid&3) ^ ((rb>>1)&3) = (tid&3) ^ ((tid>>3)&3)
  const int swsrc = ((tid & 3) ^ ((tid >> 3) & 3)) * 8;   // ushort offset
  const int rb = tid >> 2;
  int gr0 = row0 + rb;        if (gr0 > NTOK - 1) gr0 = NTOK - 1;
  int gr1 = row0 + 128 + rb;  if (gr1 > NTOK - 1) gr1 = NTOK - 1;
  const unsigned short* srcA0 = A + (size_t)gr0 * K + swsrc;
  const unsigned short* srcA1 = A + (size_t)gr1 * K + swsrc;
  const unsigned short* Bte = Bt + (size_t)e * N * K;
  const unsigned short* srcB0 = Bte + (size_t)(col0 + rb) * K + swsrc;
  const unsigned short* srcB1 = Bte + (size_t)(col0 + 128 + rb) * K + swsrc;

  // ds_read swizzled slot (per-lane constant): fj ^ ((fr>>1)&3)
  const int js = (fj ^ ((fr >> 1) & 3)) * 8;

  f32x4 acc[8][NF];
#pragma unroll
  for (int m = 0; m < 8; ++m)
#pragma unroll
    for (int n = 0; n < NF; ++n) acc[m][n] = f32x4{0.f, 0.f, 0.f, 0.f};

  auto stage = [&](unsigned short* nA, unsigned short* nB, int kel) {
    load_lds16(srcA0 + kel, nA + tid * 8);
    load_lds16(srcA1 + kel, nA + 4096 + tid * 8);
    load_lds16(srcB0 + kel, nB + tid * 8);
    if constexpr (ISS_B == 2) load_lds16(srcB1 + kel, nB + 4096 + tid * 8);
  };

  auto body = [&](const unsigned short* pA, const unsigned short* pB,
                  unsigned short* nA, unsigned short* nB, int knext,
                  bool do_stage) {
    __builtin_amdgcn_s_barrier();
    asm volatile("" ::: "memory");
    if (do_stage) stage(nA, nB, knext);   // issue ASAP; lands >=3 phases later
    s16x8 af[8], bf[NF];
#pragma unroll
    for (int m = 0; m < 8; ++m)
      af[m] = *(const s16x8*)(pA + (wm * 128 + m * 16 + fr) * 32 + js);
#pragma unroll
    for (int n = 0; n < NF; ++n)
      bf[n] = *(const s16x8*)(pB + (wn * NF * 16 + n * 16 + fr) * 32 + js);
    __builtin_amdgcn_s_setprio(1);
#pragma unroll
    for (int m = 0; m < 8; ++m)
#pragma unroll
      for (int n = 0; n < NF; ++n)
        acc[m][n] = __builtin_amdgcn_mfma_f32_16x16x32_bf16(af[m], bf[n],
                                                            acc[m][n], 0, 0, 0);
    __builtin_amdgcn_s_setprio(0);
  };

  // prologue: 3 tiles in flight (3*S VMEM instrs outstanding per wave)
  stage(As0, Bs0, 0);
  stage(As1, Bs1, 32);
  stage(As2, Bs2, 64);

#pragma unroll 1
  for (int t = 0; t < NT - 4; t += 4) {
    wait_vm<2 * S>(); body(As0, Bs0, As3, Bs3, (t + 3) * 32, true);
    wait_vm<2 * S>(); body(As1, Bs1, As0, Bs0, (t + 4) * 32, true);
    wait_vm<2 * S>(); body(As2, Bs2, As1, Bs1, (t + 5) * 32, true);
    wait_vm<2 * S>(); body(As3, Bs3, As2, Bs2, (t + 6) * 32, true);
  }
  // tail: tiles NT-4 .. NT-1
  wait_vm<2 * S>(); body(As0, Bs0, As3, Bs3, (NT - 1) * 32, true);
  wait_vm<2 * S>(); body(As1, Bs1, nullptr, nullptr, 0, false);
  wait_vm<S>();     body(As2, Bs2, nullptr, nullptr, 0, false);
  wait_vm<0>();     body(As3, Bs3, nullptr, nullptr, 0, false);

  // epilogue
#pragma unroll
  for (int n = 0; n < NF; ++n) {
    const int col = col0 + wn * NF * 16 + n * 16 + fr;
    const float bv = bias[e * N + col];
#pragma unroll
    for (int m = 0; m < 8; ++m) {
#pragma unroll
      for (int j = 0; j < 4; ++j) {
        const int rl = wm * 128 + m * 16 + fj * 4 + j;
        if (bx * BM + rl < cnt) {
          if constexpr (FUSE1) {
            outb[(size_t)(row0 + rl) * N + col] = f2bf(fmaxf(acc[m][n][j] + bv, 0.f));
          } else {
            outf[(size_t)stok[row0 + rl] * N + col] = acc[m][n][j] + bv;
          }
        }
      }
    }
  }
}

extern "C" void kernel_launch(void* const* d_in, const int* in_sizes, int n_in,
                              void* d_out, int out_size, void* d_ws, size_t ws_size,
                              hipStream_t stream) {
  (void)in_sizes; (void)n_in; (void)out_size;
  const float* x  = (const float*)d_in[0];
  const float* Wg = (const float*)d_in[1];
  const float* bg = (const float*)d_in[2];
  const float* W1 = (const float*)d_in[3];
  const float* b1 = (const float*)d_in[4];
  const float* W2 = (const float*)d_in[5];
  const float* b2 = (const float*)d_in[6];
  float* out = (float*)d_out;

  char* ws = (char*)d_ws;
  const size_t OFF_CNT = 0;                                    // 8 ints
  const size_t OFF_OFF = 128;                                  // offs[0..9]
  const size_t OFF_WL  = 256;                                  // MAXWL ints
  const size_t OFF_LST = 1024;                                 // E*NTOK ints (256 KB)
  const size_t OFF_STK = OFF_LST + (size_t)NEXP * NTOK * 4;    // NTOK ints
  const size_t OFF_XBS = OFF_STK + (size_t)NTOK * 4;           // NTOK*D bf16 (16 MB)
  const size_t OFF_HS  = OFF_XBS + (size_t)NTOK * DDIM * 2;    // NTOK*H bf16 (64 MB)
  const size_t OFF_WT  = OFF_HS + (size_t)NTOK * HDIM * 2;     // E*D*H bf16 (64 MB)
  const size_t NEED    = OFF_WT + (size_t)NEXP * DDIM * HDIM * 2;
  if (ws_size < NEED) return;

  int* counts = (int*)(ws + OFF_CNT);
  int* offs   = (int*)(ws + OFF_OFF);
  int* wl     = (int*)(ws + OFF_WL);
  int* lists  = (int*)(ws + OFF_LST);
  int* stok   = (int*)(ws + OFF_STK);
  unsigned short* xbs = (unsigned short*)(ws + OFF_XBS);
  unsigned short* Hs  = (unsigned short*)(ws + OFF_HS);
  unsigned short* Wt  = (unsigned short*)(ws + OFF_WT);

  hipMemsetAsync(counts, 0, 128, stream);
  gate_kernel<<<NTOK / 4, 256, 0, stream>>>(x, Wg, bg, counts, lists);
  offs_kernel<<<1, 1, 0, stream>>>(counts, offs, wl);
  gather_conv_kernel<<<NTOK / 4, 256, 0, stream>>>(x, offs, lists, stok, xbs);

  // W1 [E][D][H] -> Wt [E][H][D]
  transpose_conv_kernel<<<dim3(HDIM / 64, DDIM / 64, NEXP), 256, 0, stream>>>(
      W1, Wt, DDIM, HDIM);
  // ffn1: Hs[pos] = relu(xbs[pos] @ W1[e] + b1[e]) ; 256x256, depth-3 pipeline
  ffn_kernel<256, DDIM, HDIM, true>
      <<<dim3((HDIM / 256) * MAXWL), 512, 0, stream>>>(
          xbs, Wt, b1, counts, offs, wl, stok, Hs, nullptr);
  // W2 [E][H][D] -> Wt [E][D][H]  (reuse buffer after ffn1)
  transpose_conv_kernel<<<dim3(DDIM / 64, HDIM / 64, NEXP), 256, 0, stream>>>(
      W2, Wt, HDIM, DDIM);
  // ffn2: out[stok[pos]] = Hs[pos] @ W2[e] + b2[e] ; 256x128, depth-3 pipeline
  ffn_kernel<128, HDIM, DDIM, false>
      <<<dim3((DDIM / 128) * MAXWL), 512, 0, stream>>>(
          Hs, Wt, b2, counts, offs, wl, stok, nullptr, out);
}

// Round 10
// 453.048 us; speedup vs baseline: 1.1972x; 1.1248x over previous
//
#include <hip/hip_runtime.h>
#include <hip/hip_bf16.h>
#include <stdint.h>

#define NTOK 8192
#define DDIM 1024
#define HDIM 4096
#define NEXP 8
#define MAXWL1 48   // BM=256 work-list
#define MAXWL2 72   // BM=128 work-list

typedef __attribute__((ext_vector_type(4))) float f32x4;
typedef __attribute__((ext_vector_type(8))) short s16x8;
typedef __attribute__((ext_vector_type(8))) unsigned short u16x8;

__device__ __forceinline__ unsigned short f2bf(float f) {
  union { float f; unsigned int u; } v; v.f = f;
  unsigned int u = v.u;
  u += 0x7FFFu + ((u >> 16) & 1u);   // round-to-nearest-even
  return (unsigned short)(u >> 16);
}

typedef __attribute__((address_space(3))) unsigned char lds_u8;
typedef const __attribute__((address_space(1))) unsigned char glb_u8;

__device__ __forceinline__ void load_lds16(const void* g, void* l) {
  __builtin_amdgcn_global_load_lds((glb_u8*)g, (lds_u8*)l, 16, 0, 0);
}

// ---------------- gate + top-1 routing ----------------
__global__ __launch_bounds__(256) void gate_kernel(
    const float* __restrict__ x, const float* __restrict__ Wg,
    const float* __restrict__ bg, int* __restrict__ counts,
    int* __restrict__ lists) {
  const int lane = threadIdx.x & 63;
  const int tok = blockIdx.x * 4 + (threadIdx.x >> 6);
  const float* xr = x + (size_t)tok * DDIM;
  double acc[NEXP];
#pragma unroll
  for (int e = 0; e < NEXP; ++e) acc[e] = 0.0;
#pragma unroll 4
  for (int it = 0; it < DDIM / 64; ++it) {
    const int d = it * 64 + lane;
    const float xv = xr[d];
    const f32x4 w0 = *(const f32x4*)(Wg + (size_t)d * NEXP);
    const f32x4 w1 = *(const f32x4*)(Wg + (size_t)d * NEXP + 4);
#pragma unroll
    for (int j = 0; j < 4; ++j) {
      acc[j]     += (double)xv * (double)w0[j];
      acc[4 + j] += (double)xv * (double)w1[j];
    }
  }
#pragma unroll
  for (int e = 0; e < NEXP; ++e) {
    double v = acc[e];
#pragma unroll
    for (int off = 32; off > 0; off >>= 1) v += __shfl_xor(v, off, 64);
    acc[e] = v;
  }
  if (lane == 0) {
    int best = 0;
    double bv = acc[0] + (double)bg[0];
#pragma unroll
    for (int e = 1; e < NEXP; ++e) {
      const double v = acc[e] + (double)bg[e];
      if (v > bv) { bv = v; best = e; }   // strict > : first max wins (np argmax)
    }
    const int pos = atomicAdd(&counts[best], 1);
    lists[best * NTOK + pos] = tok;
  }
}

// ---- prefix sum + two work-lists: wl1 (BM=256), wl2 (BM=128) ----
__global__ void offs_kernel(const int* __restrict__ counts, int* __restrict__ offs,
                            int* __restrict__ wl1, int* __restrict__ wl2) {
  int s = 0;
#pragma unroll
  for (int e = 0; e < NEXP; ++e) { offs[e] = s; s += counts[e]; }
  offs[NEXP] = s;
  int n1 = 0, n2 = 0;
  for (int e = 0; e < NEXP; ++e) {
    const int nb1 = (counts[e] + 255) >> 8;
    for (int b = 0; b < nb1; ++b) wl1[n1++] = (e << 20) | b;
    const int nb2 = (counts[e] + 127) >> 7;
    for (int b = 0; b < nb2; ++b) wl2[n2++] = (e << 20) | b;
  }
  offs[NEXP + 1] = n1;
  offs[NEXP + 2] = n2;
}

// -------- gather tokens into expert-sorted order, convert to bf16 --------
__global__ __launch_bounds__(256) void gather_conv_kernel(
    const float* __restrict__ x, const int* __restrict__ offs,
    const int* __restrict__ lists, int* __restrict__ stok,
    unsigned short* __restrict__ xbs) {
  const int p = blockIdx.x * 4 + (threadIdx.x >> 6);   // sorted position
  const int lane = threadIdx.x & 63;
  int e = 0;
#pragma unroll
  for (int k = 1; k < NEXP; ++k) e += (p >= offs[k]) ? 1 : 0;
  const int tok = lists[e * NTOK + (p - offs[e])];
  if (lane == 0) stok[p] = tok;
  const float* src = x + (size_t)tok * DDIM + lane * 16;
  unsigned short* dst = xbs + (size_t)p * DDIM + lane * 16;
#pragma unroll
  for (int q = 0; q < 2; ++q) {
    const f32x4 a = *(const f32x4*)(src + q * 8);
    const f32x4 b = *(const f32x4*)(src + q * 8 + 4);
    u16x8 o;
#pragma unroll
    for (int j = 0; j < 4; ++j) { o[j] = f2bf(a[j]); o[4 + j] = f2bf(b[j]); }
    *(u16x8*)(dst + q * 8) = o;
  }
}

// -- transpose + convert: in [E][R][C] fp32 -> out [E][C][R] bf16; 16B writes --
__global__ __launch_bounds__(256) void transpose_conv_kernel(
    const float* __restrict__ in, unsigned short* __restrict__ out,
    int R, int C) {
  __shared__ unsigned short T[64][66];
  const int e = blockIdx.z;
  const float* ine = in + (size_t)e * R * C;
  unsigned short* oute = out + (size_t)e * C * R;
  const int c0 = blockIdx.x * 64, r0 = blockIdx.y * 64;
  const int t = threadIdx.x;
  const int tr = t >> 4, tc4 = (t & 15) * 4;
#pragma unroll
  for (int p = 0; p < 4; ++p) {
    const int r = tr + p * 16;
    const f32x4 v = *(const f32x4*)(ine + (size_t)(r0 + r) * C + c0 + tc4);
#pragma unroll
    for (int j = 0; j < 4; ++j) T[r][tc4 + j] = f2bf(v[j]);
  }
  __syncthreads();
  const int cc = t >> 3, rr8 = (t & 7) * 8;
#pragma unroll
  for (int p = 0; p < 2; ++p) {
    const int c = cc + p * 32;
    u16x8 o;
#pragma unroll
    for (int j = 0; j < 8; ++j) o[j] = T[rr8 + j][c];
    *(u16x8*)(oute + (size_t)(c0 + c) * R + r0 + rr8) = o;
  }
}

// ---- grouped GEMM: 32K-output tiles, ring-2, depth-1 (R5 schedule), 2 blk/CU ----
// A: bf16 [NTOK][K] expert-sorted rows. Bt: bf16 [E][N][K] (K-contiguous rows).
// Per-wave 64x64 output (acc=64 VGPR -> <=128 total -> 4 waves/SIMD -> 2 blk/CU).
// Phase: vmcnt(0)+barrier -> 8x ds_read (clean swizzle, 0 conflicts measured R9)
//        -> stage next tile (flies under MFMA + other block's compute) -> 16 MFMA.
// COLFAST: col-fastest XCD order (A-reuse, for ffn2); else wli-fastest (B-reuse).
template <int BM, int BN, int WM, int WN, int K, int N, int MAXWLT,
          bool COLFAST, bool FUSE1>
__global__ __launch_bounds__(512, 4) void ffn_kernel(
    const unsigned short* __restrict__ A, const unsigned short* __restrict__ Bt,
    const float* __restrict__ bias, const int* __restrict__ counts,
    const int* __restrict__ offs, const int* __restrict__ wl,
    const int* __restrict__ stok, unsigned short* __restrict__ outb,
    float* __restrict__ outf, int nwl_idx) {
  constexpr int MF = BM / (WM * 16);   // 4
  constexpr int NF = BN / (WN * 16);   // 4
  constexpr int ISS_A = BM / 128;
  constexpr int ISS_B = BN / 128;
  constexpr int NT = K / 32;
  constexpr int NCB = N / BN;
  constexpr int NWG = NCB * MAXWLT;
  static_assert((NWG & 7) == 0 && (NT & 1) == 0 && NT >= 4, "");
  static_assert(WM * WN == 8, "8 waves");

  const int d = blockIdx.x;
  const int logical = (d & 7) * (NWG / 8) + (d >> 3);  // XCD chunking
  int cb, wli;
  if constexpr (COLFAST) { cb = logical % NCB; wli = logical / NCB; }
  else                   { cb = logical / MAXWLT; wli = logical % MAXWLT; }
  if (wli >= offs[nwl_idx]) return;
  const int col0 = cb * BN;
  const int wle = wl[wli];
  const int e = wle >> 20;
  const int bx = wle & 0xFFFFF;
  const int cnt = counts[e];
  const int row0 = offs[e] + bx * BM;

  __shared__ __align__(16) unsigned short As0[BM * 32], Bs0[BN * 32];
  __shared__ __align__(16) unsigned short As1[BM * 32], Bs1[BN * 32];

  const int tid = threadIdx.x;
  const int lane = tid & 63;
  const int w = tid >> 6;
  const int wm = w / WN;
  const int wn = w % WN;
  const int fr = lane & 15;
  const int fj = lane >> 4;

  // staging: thread -> LDS row i*128+(tid>>2), 16B-slot tid&3;
  // source slot pre-swizzled by ^((row>>1)&3) = ^((tid>>3)&3)  [R9-verified clean]
  const int swsrc = ((tid & 3) ^ ((tid >> 3) & 3)) * 8;   // ushort offset
  const int rb = tid >> 2;
  const unsigned short* srcA[ISS_A];
#pragma unroll
  for (int i = 0; i < ISS_A; ++i) {
    int gr = row0 + i * 128 + rb;
    if (gr > NTOK - 1) gr = NTOK - 1;   // clamp: garbage rows masked in epilogue
    srcA[i] = A + (size_t)gr * K + swsrc;
  }
  const unsigned short* Bte = Bt + (size_t)e * N * K;
  const unsigned short* srcB[ISS_B];
#pragma unroll
  for (int i = 0; i < ISS_B; ++i)
    srcB[i] = Bte + (size_t)(col0 + i * 128 + rb) * K + swsrc;

  // ds_read swizzled 16B-slot (per-lane constant): fj ^ ((fr>>1)&3)
  const int js = (fj ^ ((fr >> 1) & 3)) * 8;

  f32x4 acc[MF][NF];
#pragma unroll
  for (int m = 0; m < MF; ++m)
#pragma unroll
    for (int n = 0; n < NF; ++n) acc[m][n] = f32x4{0.f, 0.f, 0.f, 0.f};

  auto stage = [&](unsigned short* dA, unsigned short* dB, int kel) {
#pragma unroll
    for (int i = 0; i < ISS_A; ++i)
      load_lds16(srcA[i] + kel, dA + i * 4096 + tid * 8);
#pragma unroll
    for (int i = 0; i < ISS_B; ++i)
      load_lds16(srcB[i] + kel, dB + i * 4096 + tid * 8);
  };

  auto phase = [&](const unsigned short* pA, const unsigned short* pB,
                   unsigned short* nA, unsigned short* nB, int knext,
                   bool do_stage) {
    asm volatile("s_waitcnt vmcnt(0)" ::: "memory");  // current tile landed
    __builtin_amdgcn_s_barrier();
    asm volatile("" ::: "memory");
    // read whole tile into registers BEFORE staging next (no alias waits)
    s16x8 af[MF], bf[NF];
#pragma unroll
    for (int m = 0; m < MF; ++m)
      af[m] = *(const s16x8*)(pA + (wm * MF * 16 + m * 16 + fr) * 32 + js);
#pragma unroll
    for (int n = 0; n < NF; ++n)
      bf[n] = *(const s16x8*)(pB + (wn * NF * 16 + n * 16 + fr) * 32 + js);
    if (do_stage) stage(nA, nB, knext);   // flies under MFMA + co-resident block
    __builtin_amdgcn_s_setprio(1);
#pragma unroll
    for (int m = 0; m < MF; ++m)
#pragma unroll
      for (int n = 0; n < NF; ++n)
        acc[m][n] = __builtin_amdgcn_mfma_f32_16x16x32_bf16(af[m], bf[n],
                                                            acc[m][n], 0, 0, 0);
    __builtin_amdgcn_s_setprio(0);
  };

  stage(As0, Bs0, 0);   // prologue
#pragma unroll 1
  for (int t = 0; t < NT - 2; t += 2) {
    phase(As0, Bs0, As1, Bs1, (t + 1) * 32, true);
    phase(As1, Bs1, As0, Bs0, (t + 2) * 32, true);
  }
  phase(As0, Bs0, As1, Bs1, (NT - 1) * 32, true);
  phase(As1, Bs1, nullptr, nullptr, 0, false);

  // epilogue
#pragma unroll
  for (int n = 0; n < NF; ++n) {
    const int col = col0 + wn * NF * 16 + n * 16 + fr;
    const float bv = bias[e * N + col];
#pragma unroll
    for (int m = 0; m < MF; ++m) {
#pragma unroll
      for (int j = 0; j < 4; ++j) {
        const int rl = wm * MF * 16 + m * 16 + fj * 4 + j;
        if (bx * BM + rl < cnt) {
          if constexpr (FUSE1) {
            outb[(size_t)(row0 + rl) * N + col] = f2bf(fmaxf(acc[m][n][j] + bv, 0.f));
          } else {
            outf[(size_t)stok[row0 + rl] * N + col] = acc[m][n][j] + bv;
          }
        }
      }
    }
  }
}

extern "C" void kernel_launch(void* const* d_in, const int* in_sizes, int n_in,
                              void* d_out, int out_size, void* d_ws, size_t ws_size,
                              hipStream_t stream) {
  (void)in_sizes; (void)n_in; (void)out_size;
  const float* x  = (const float*)d_in[0];
  const float* Wg = (const float*)d_in[1];
  const float* bg = (const float*)d_in[2];
  const float* W1 = (const float*)d_in[3];
  const float* b1 = (const float*)d_in[4];
  const float* W2 = (const float*)d_in[5];
  const float* b2 = (const float*)d_in[6];
  float* out = (float*)d_out;

  char* ws = (char*)d_ws;
  const size_t OFF_CNT = 0;                                    // 8 ints
  const size_t OFF_OFF = 128;                                  // offs[0..10]
  const size_t OFF_WL1 = 256;                                  // MAXWL1 ints
  const size_t OFF_WL2 = 256 + MAXWL1 * 4;                     // MAXWL2 ints
  const size_t OFF_LST = 1024;                                 // E*NTOK ints (256 KB)
  const size_t OFF_STK = OFF_LST + (size_t)NEXP * NTOK * 4;    // NTOK ints
  const size_t OFF_XBS = OFF_STK + (size_t)NTOK * 4;           // NTOK*D bf16 (16 MB)
  const size_t OFF_HS  = OFF_XBS + (size_t)NTOK * DDIM * 2;    // NTOK*H bf16 (64 MB)
  const size_t OFF_WT  = OFF_HS + (size_t)NTOK * HDIM * 2;     // E*D*H bf16 (64 MB)
  const size_t NEED    = OFF_WT + (size_t)NEXP * DDIM * HDIM * 2;
  if (ws_size < NEED) return;

  int* counts = (int*)(ws + OFF_CNT);
  int* offs   = (int*)(ws + OFF_OFF);
  int* wl1    = (int*)(ws + OFF_WL1);
  int* wl2    = (int*)(ws + OFF_WL2);
  int* lists  = (int*)(ws + OFF_LST);
  int* stok   = (int*)(ws + OFF_STK);
  unsigned short* xbs = (unsigned short*)(ws + OFF_XBS);
  unsigned short* Hs  = (unsigned short*)(ws + OFF_HS);
  unsigned short* Wt  = (unsigned short*)(ws + OFF_WT);

  hipMemsetAsync(counts, 0, 128, stream);
  gate_kernel<<<NTOK / 4, 256, 0, stream>>>(x, Wg, bg, counts, lists);
  offs_kernel<<<1, 1, 0, stream>>>(counts, offs, wl1, wl2);
  gather_conv_kernel<<<NTOK / 4, 256, 0, stream>>>(x, offs, lists, stok, xbs);

  // W1 [E][D][H] -> Wt [E][H][D]
  transpose_conv_kernel<<<dim3(HDIM / 64, DDIM / 64, NEXP), 256, 0, stream>>>(
      W1, Wt, DDIM, HDIM);
  // ffn1: 256x128 tile, wli-fastest (B-panel L2 reuse), 1056 active blocks
  ffn_kernel<256, 128, 4, 2, DDIM, HDIM, MAXWL1, false, true>
      <<<dim3((HDIM / 128) * MAXWL1), 512, 0, stream>>>(
          xbs, Wt, b1, counts, offs, wl1, stok, Hs, nullptr, NEXP + 1);
  // W2 [E][H][D] -> Wt [E][D][H]  (reuse buffer after ffn1)
  transpose_conv_kernel<<<dim3(DDIM / 64, HDIM / 64, NEXP), 256, 0, stream>>>(
      W2, Wt, HDIM, DDIM);
  // ffn2: 128x256 tile, col-fastest (A-tile L2 reuse), 264 active blocks
  ffn_kernel<128, 256, 2, 4, HDIM, DDIM, MAXWL2, true, false>
      <<<dim3((DDIM / 256) * MAXWL2), 512, 0, stream>>>(
          Hs, Wt, b2, counts, offs, wl2, stok, nullptr, out, NEXP + 2);
}